// Round 7
// baseline (27032.858 us; speedup 1.0000x reference)
//
#include <hip/hip_runtime.h>
#include <math.h>

#define T_STEPS 512
#define BATCH   128
#define HDIM    300
#define M       20
#define M2      10   // j's owned per block

// ---------------- JAX threefry2x32 noise replication ----------------
__device__ __forceinline__ unsigned rotl32(unsigned v, int r) {
    return (v << r) | (v >> (32 - r));
}

__device__ float jax_noise(unsigned i) {
#pragma clang fp contract(off)
    unsigned x0 = 0u;
    unsigned x1 = i;
    const unsigned ks0 = 0u, ks1 = 42u, ks2 = 0u ^ 42u ^ 0x1BD11BDAu;
    x0 += ks0; x1 += ks1;
    x0 += x1; x1 = rotl32(x1, 13); x1 ^= x0;
    x0 += x1; x1 = rotl32(x1, 15); x1 ^= x0;
    x0 += x1; x1 = rotl32(x1, 26); x1 ^= x0;
    x0 += x1; x1 = rotl32(x1, 6);  x1 ^= x0;
    x0 += ks1; x1 += ks2 + 1u;
    x0 += x1; x1 = rotl32(x1, 17); x1 ^= x0;
    x0 += x1; x1 = rotl32(x1, 29); x1 ^= x0;
    x0 += x1; x1 = rotl32(x1, 16); x1 ^= x0;
    x0 += x1; x1 = rotl32(x1, 24); x1 ^= x0;
    x0 += ks2; x1 += ks0 + 2u;
    x0 += x1; x1 = rotl32(x1, 13); x1 ^= x0;
    x0 += x1; x1 = rotl32(x1, 15); x1 ^= x0;
    x0 += x1; x1 = rotl32(x1, 26); x1 ^= x0;
    x0 += x1; x1 = rotl32(x1, 6);  x1 ^= x0;
    x0 += ks0; x1 += ks1 + 3u;
    x0 += x1; x1 = rotl32(x1, 17); x1 ^= x0;
    x0 += x1; x1 = rotl32(x1, 29); x1 ^= x0;
    x0 += x1; x1 = rotl32(x1, 16); x1 ^= x0;
    x0 += x1; x1 = rotl32(x1, 24); x1 ^= x0;
    x0 += ks1; x1 += ks2 + 4u;
    x0 += x1; x1 = rotl32(x1, 13); x1 ^= x0;
    x0 += x1; x1 = rotl32(x1, 15); x1 ^= x0;
    x0 += x1; x1 = rotl32(x1, 26); x1 ^= x0;
    x0 += x1; x1 = rotl32(x1, 6);  x1 ^= x0;
    x0 += ks2; x1 += ks0 + 5u;

    const unsigned bits = x0 ^ x1;
    const unsigned fb = (bits >> 9) | 0x3f800000u;
    float f = __uint_as_float(fb) - 1.0f;
    const float span = 1.0f - 0.01f;
    float v = f * span;
    v = v + 0.01f;
    return fmaxf(0.01f, v);
}

#define FOR5(X) X(0) X(1) X(2) X(3) X(4)

// ---------------- paired persistent kernel, concurrent A||B ----------------
// grid = 256 blocks: bid -> batch b = bid&127, j-half = bid>>7 (rows jb2..jb2+9).
// Partner bid^128 (same XCD under %8 round-robin). Exchange 10 sim floats/step.
//
// Wave roles (R7):
//   waves 0-4  (G, tid 0-319, active <300): Phase B GEMM, 2 cols x 5 j's per
//     thread (16 FMAs per sh_mem broadcast read; R5-proven loop, reg prefetch).
//   waves 5-9  (V, tid 320-639, active cA<300): Phase A (hb1+ent+hwu GEMVs,
//     CONCURRENT with B), then sim-finish and Phase D (hold hb1reg/hwureg).
// h read straight from global (L1-resident 1.2KB row) -> no sh_h, 4 barriers.
// LDS padded >80KB => exactly 1 block/CU => all 256 blocks resident (spin-safe)
// and 3-waves/SIMD register budget (~168).
__global__ void __launch_bounds__(640, 3)
wm_kernel(const float* __restrict__ hs,   // (T,B,H)
          const float* __restrict__ msk,  // (T,B)
          const float* __restrict__ We1,  // (300,300)
          const float* __restrict__ be1,  // (300)
          const float* __restrict__ We2,  // (300,1)
          const float* __restrict__ be2,  // (1)
          const float* __restrict__ Ws1,  // (901,300)
          const float* __restrict__ bs1,  // (300)
          const float* __restrict__ Ws2,  // (300,1)
          const float* __restrict__ bs2,  // (1)
          const float* __restrict__ Wu,   // (600,300)
          const float* __restrict__ bu,   // (300)
          float* __restrict__ out,
          float* __restrict__ ws)         // d_ws: vals[256][16] @0, flags @+16KB
{
    __shared__ __align__(16) float sh_mem[M2][HDIM];
    __shared__ __align__(16) float sh_sim[M2][HDIM];
    __shared__ __align__(16) float sh_cand[M2][HDIM];
    __shared__ __align__(16) float sh_usage[12288];  // [M] used; oversized -> LDS >80KB
    __shared__ float sh_simpart[5][M2];
    __shared__ float sh_entpart[5];
    __shared__ float sh_ow[M];
    __shared__ float sh_indv[M];

    const int bid   = blockIdx.x;
    const int b     = bid & 127;
    const int jhalf = bid >> 7;
    const int jb2   = jhalf * 10;         // own global j-base
    const int pbase = 10 - jb2;           // partner global j-base
    const int pbid  = bid ^ 128;

    float*    vals_me = ws + (size_t)bid * 16;
    float*    vals_p  = ws + (size_t)pbid * 16;
    unsigned* flag_me = (unsigned*)(ws + 4096) + (size_t)bid * 16;
    unsigned* flag_p  = (unsigned*)(ws + 4096) + (size_t)pbid * 16;

    const int tid  = threadIdx.x;
    const int wave = tid >> 6;   // 0..9
    const int lane = tid & 63;

    // ---- G group (Phase B): 2 j-groups (5 j's) x 150 column-pairs ----
    const bool isG  = tid < 320;
    const bool actG = tid < 300;
    const int  jgB  = tid / 150;          // 0 or 1 (for active)
    const int  pB   = tid % 150;
    const int  c0   = 2 * pB;             // columns c0, c0+1
    const int  jl   = jgB * 5;            // local j-base

    // ---- V group (Phase A / sim-finish / Phase D) ----
    const int  cA    = tid - 320;         // 0..319
    const bool actV  = (tid >= 320) && (cA < HDIM);
    const int  vwave = wave - 5;          // 0..4 for V waves

    // ---- init state ----
    for (int idx = tid; idx < M2 * HDIM; idx += 640) ((float*)sh_mem)[idx] = 0.0f;
    if (tid < M) sh_usage[tid] = 0.0f;

    const float be2v = be2[0];
    const float bs2v = bs2[0];
    // step-invariant per-column scalars (V threads only)
    float bs1c = 0.f, be1c = 0.f, we2c = 0.f, ws2c = 0.f, w900c = 0.f, buc = 0.f;
    if (actV) {
        bs1c = bs1[cA]; be1c = be1[cA]; we2c = We2[cA];
        ws2c = Ws2[cA]; w900c = Ws1[900 * 300 + cA];
        buc  = bu[cA];
    }
    __syncthreads();

    for (int t = 0; t < T_STEPS; ++t) {
        const int tb = t * BATCH + b;
        const float* __restrict__ hrow = hs + (size_t)tb * HDIM;   // L1-resident

        float hb1reg = 0.f, hwureg = 0.f;

        if (isG) {
            // ---- Phase B: fused sim+cand, 2 cols x 5 local j's x full K ----
#define DECL_ACC(jj) float aS0_##jj = 0.f, aS1_##jj = 0.f, aC0_##jj = 0.f, aC1_##jj = 0.f;
            FOR5(DECL_ACC)
#undef DECL_ACC
            if (actG) {
                const float* qa = Ws1 + c0;            // rows 0..299   (mem)
                const float* qc = Ws1 + 180000 + c0;   // rows 600..899 (h*mem)
                const float* qu = Wu + 90000 + c0;     // rows 300..599 (mem)
                float2 A0 = *(const float2*)(qa);
                float2 A1 = *(const float2*)(qa + 300);
                float2 A2 = *(const float2*)(qa + 600);
                float2 A3 = *(const float2*)(qa + 900);
                float2 C0 = *(const float2*)(qc);
                float2 C1 = *(const float2*)(qc + 300);
                float2 C2 = *(const float2*)(qc + 600);
                float2 C3 = *(const float2*)(qc + 900);
                float2 U0 = *(const float2*)(qu);
                float2 U1 = *(const float2*)(qu + 300);
                float2 U2 = *(const float2*)(qu + 600);
                float2 U3 = *(const float2*)(qu + 900);
                for (int k = 0; k < HDIM; k += 4) {
                    const int kn = (k + 4 < HDIM) ? (k + 4) : 0;   // clamped prefetch
                    const float* na = qa + kn * 300;
                    const float* nc = qc + kn * 300;
                    const float* nu = qu + kn * 300;
                    float2 NA0 = *(const float2*)(na);
                    float2 NA1 = *(const float2*)(na + 300);
                    float2 NA2 = *(const float2*)(na + 600);
                    float2 NA3 = *(const float2*)(na + 900);
                    float2 NC0 = *(const float2*)(nc);
                    float2 NC1 = *(const float2*)(nc + 300);
                    float2 NC2 = *(const float2*)(nc + 600);
                    float2 NC3 = *(const float2*)(nc + 900);
                    float2 NU0 = *(const float2*)(nu);
                    float2 NU1 = *(const float2*)(nu + 300);
                    float2 NU2 = *(const float2*)(nu + 600);
                    float2 NU3 = *(const float2*)(nu + 900);

                    float4 h4 = *(const float4*)&hrow[k];
                    float w00 = fmaf(h4.x, C0.x, A0.x);
                    float w01 = fmaf(h4.y, C1.x, A1.x);
                    float w02 = fmaf(h4.z, C2.x, A2.x);
                    float w03 = fmaf(h4.w, C3.x, A3.x);
                    float w10 = fmaf(h4.x, C0.y, A0.y);
                    float w11 = fmaf(h4.y, C1.y, A1.y);
                    float w12 = fmaf(h4.z, C2.y, A2.y);
                    float w13 = fmaf(h4.w, C3.y, A3.y);
#define ACC_J(jj) { \
                    float4 mv = *(const float4*)&sh_mem[jl + jj][k]; \
                    aS0_##jj += mv.x * w00 + mv.y * w01 + mv.z * w02 + mv.w * w03; \
                    aS1_##jj += mv.x * w10 + mv.y * w11 + mv.z * w12 + mv.w * w13; \
                    aC0_##jj += mv.x * U0.x + mv.y * U1.x + mv.z * U2.x + mv.w * U3.x; \
                    aC1_##jj += mv.x * U0.y + mv.y * U1.y + mv.z * U2.y + mv.w * U3.y; }
                    FOR5(ACC_J)
#undef ACC_J
                    A0 = NA0; A1 = NA1; A2 = NA2; A3 = NA3;
                    C0 = NC0; C1 = NC1; C2 = NC2; C3 = NC3;
                    U0 = NU0; U1 = NU1; U2 = NU2; U3 = NU3;
                }
#define WB(jj) { \
                *(float2*)&sh_sim[jl + jj][c0]  = make_float2(aS0_##jj, aS1_##jj); \
                *(float2*)&sh_cand[jl + jj][c0] = make_float2(aC0_##jj, aC1_##jj); }
                FOR5(WB)
#undef WB
            }
        } else {
            // ---- Phase A (concurrent with B): 3 GEMVs per thread ----
            float a1 = 0.f, ae = 0.f, au = 0.f;
            if (actV) {
                const float* pB_ = Ws1 + 90000 + cA;   // rows 300..599
                const float* pE  = We1 + cA;
                const float* pU  = Wu + cA;            // rows 0..299
                for (int k = 0; k < HDIM; k += 4) {
                    float4 h4 = *(const float4*)&hrow[k];
                    const float* q  = pB_ + k * 300;
                    const float* qe = pE + k * 300;
                    const float* qq = pU + k * 300;
                    a1 += h4.x * q[0]  + h4.y * q[300]  + h4.z * q[600]  + h4.w * q[900];
                    ae += h4.x * qe[0] + h4.y * qe[300] + h4.z * qe[600] + h4.w * qe[900];
                    au += h4.x * qq[0] + h4.y * qq[300] + h4.z * qq[600] + h4.w * qq[900];
                }
            }
            float er = actV ? (fmaxf(ae + be1c, 0.0f) * we2c) : 0.0f;
            for (int off = 32; off; off >>= 1) er += __shfl_xor(er, off, 64);
            if (lane == 0) sh_entpart[vwave] = er;
            hb1reg = a1 + bs1c;
            hwureg = au + buc;
        }
        __syncthreads();   // (1) sim/cand partials + entpart ready

        // ---- sim finish: relu(.)*Ws2, reduce over columns (V waves) ----
        if (!isG) {
#pragma unroll
            for (int jj = 0; jj < M2; ++jj) {
                float v = 0.f;
                if (actV) {
                    float pre = sh_sim[jj][cA] + hb1reg + sh_usage[jb2 + jj] * w900c;
                    v = fmaxf(pre, 0.0f) * ws2c;
                }
                for (int off = 32; off; off >>= 1) v += __shfl_xor(v, off, 64);
                if (lane == 0) sh_simpart[vwave][jj] = v;
            }
        }
        __syncthreads();   // (2)

        // ---- Phase C: exchange + decision (wave 0; redundant on both halves) ----
        if (wave == 0) {
            float sown = 0.f;
            if (lane < M2) {
                sown = sh_simpart[0][lane] + sh_simpart[1][lane] + sh_simpart[2][lane]
                     + sh_simpart[3][lane] + sh_simpart[4][lane];
                __hip_atomic_store(&vals_me[lane], sown, __ATOMIC_RELAXED,
                                   __HIP_MEMORY_SCOPE_AGENT);
            }
            if (lane == 0) {
                __hip_atomic_store(flag_me, (unsigned)(t + 1), __ATOMIC_RELEASE,
                                   __HIP_MEMORY_SCOPE_AGENT);
                while (__hip_atomic_load(flag_p, __ATOMIC_ACQUIRE,
                                         __HIP_MEMORY_SCOPE_AGENT) < (unsigned)(t + 1))
                    __builtin_amdgcn_s_sleep(1);
            }
            float pvv = 0.f;
            if (lane >= pbase && lane < pbase + M2)
                pvv = __hip_atomic_load(&vals_p[lane - pbase], __ATOMIC_ACQUIRE,
                                        __HIP_MEMORY_SCOPE_AGENT);
            const float myv = __shfl(sown, lane - jb2, 64);

            const bool act = lane < M;
            const bool own = act && (lane >= jb2) && (lane < jb2 + M2);
            float simj = -INFINITY, usg = 0.0f;
            if (act) {
                simj = (own ? myv : pvv) + bs2v;
                usg  = sh_usage[lane];
            }
            float es = sh_entpart[0] + sh_entpart[1] + sh_entpart[2]
                     + sh_entpart[3] + sh_entpart[4] + be2v;
            const float entp = (1.0f / (1.0f + expf(-es))) * msk[tb];

            const float coref = (act && usg > 0.0f) ? 1.0f : 0.0f;
            float comb = act ? ((usg > 0.0f) ? simj : -10000.0f) : -INFINITY;
            float mx = comb;
            for (int off = 32; off; off >>= 1) mx = fmaxf(mx, __shfl_xor(mx, off, 64));
            mx = fmaxf(mx, 0.0f);
            float e = act ? expf(comb - mx) : 0.0f;
            const float eM = expf(0.0f - mx);
            float den = e;
            for (int off = 32; off; off >>= 1) den += __shfl_xor(den, off, 64);
            den += eM;
            const float prob  = e / den;
            const float probM = eM / den;
            float masked = prob * coref;
            float msum = masked;
            for (int off = 32; off; off >>= 1) msum += __shfl_xor(msum, off, 64);
            msum += probM;
            const float dn = msum + 1e-8f;
            const float normj = masked / dn;
            const float normM = probM / dn;
            const float indv = act ? (entp * normj) : 0.0f;
            const float ow_base = entp * normM;

            // nsim = softmax(sim)
            float nmx = simj;
            for (int off = 32; off; off >>= 1) nmx = fmaxf(nmx, __shfl_xor(nmx, off, 64));
            float ne = act ? expf(simj - nmx) : 0.0f;
            float ns = ne;
            for (int off = 32; off; off >>= 1) ns += __shfl_xor(ns, off, 64);
            const float nsim = ne / ns;

            float ows = act ? (((usg == 0.0f) ? nsim * 100000.0f : 0.0f) + (1.0f - usg))
                            : -INFINITY;
            float mv = ows;
            for (int off = 32; off; off >>= 1) mv = fmaxf(mv, __shfl_xor(mv, off, 64));

            float key = 0.0f;
            if (act && ows == mv) key = jax_noise((unsigned)(tb * M + lane));
            float bv = act ? key : -1.0f;
            int bi = act ? lane : 1023;
            for (int off = 32; off; off >>= 1) {
                float ov = __shfl_xor(bv, off, 64);
                int oi = __shfl_xor(bi, off, 64);
                if (ov > bv || (ov == bv && oi < bi)) { bv = ov; bi = oi; }
            }
            const float ow = (act && lane == bi) ? ow_base : 0.0f;
            const float nu = fminf(1.0f, (ow + indv) + 0.98f * usg);

            if (act) {
                sh_ow[lane] = ow;
                sh_indv[lane] = indv;
                sh_usage[lane] = nu;
            }
            if (own) {
                const int base = tb * M + lane;
                out[65536 + base]   = nu;                                   // usage_seq
                out[1376256 + base] = indv * (1.0f - 1e-8f) + 1e-8f;        // coref
                out[2686976 + base] = ow * (1.0f - 1e-8f) + 1e-8f;          // overwrite
            }
            if (jhalf == 0 && lane == 0) out[tb] = entp * (1.0f - 1e-8f) + 1e-8f; // ent
        }
        __syncthreads();   // (3)

        // ---- Phase D: memory update (V threads; own 10 j's) ----
        if (actV) {
            const float hc = hrow[cA];
#pragma unroll
            for (int jj = 0; jj < M2; ++jj) {
                const float owj = sh_ow[jb2 + jj];
                const float inj = sh_indv[jb2 + jj];
                const float cd  = tanhf(sh_cand[jj][cA] + hwureg);
                const float mo  = sh_mem[jj][cA];
                sh_mem[jj][cA] = owj * hc + (1.0f - owj - inj) * mo + inj * cd;
            }
        }
        __syncthreads();   // (4)
    }
}

extern "C" void kernel_launch(void* const* d_in, const int* in_sizes, int n_in,
                              void* d_out, int out_size, void* d_ws, size_t ws_size,
                              hipStream_t stream) {
    (void)in_sizes; (void)n_in; (void)ws_size; (void)out_size;
    const float* hs  = (const float*)d_in[0];
    const float* msk = (const float*)d_in[1];
    const float* We1 = (const float*)d_in[2];
    const float* be1 = (const float*)d_in[3];
    const float* We2 = (const float*)d_in[4];
    const float* be2 = (const float*)d_in[5];
    const float* Ws1 = (const float*)d_in[6];
    const float* bs1 = (const float*)d_in[7];
    const float* Ws2 = (const float*)d_in[8];
    const float* bs2 = (const float*)d_in[9];
    const float* Wu  = (const float*)d_in[10];
    const float* bu  = (const float*)d_in[11];
    float* out = (float*)d_out;

    // zero the sync flags/vals (stream-ordered, graph-capturable)
    hipMemsetAsync(d_ws, 0, 64 * 1024, stream);
    hipLaunchKernelGGL(wm_kernel, dim3(256), dim3(640), 0, stream,
                       hs, msk, We1, be1, We2, be2, Ws1, bs1, Ws2, bs2, Wu, bu,
                       out, (float*)d_ws);
}